// Round 4
// baseline (1069.659 us; speedup 1.0000x reference)
//
#include <hip/hip_runtime.h>
#include <hip/hip_bf16.h>

#define D_OUT 64
#define K_DIM 512
#define RPB 128            // rows per bucket (pow2)
#define RPB_SHIFT 7
#define EPB 8192           // edges per partition block

using short8  = __attribute__((ext_vector_type(8))) short;
using floatx4 = __attribute__((ext_vector_type(4))) float;

__device__ inline unsigned short f32_to_bf16(float f) {
    unsigned int u = __float_as_uint(f);
    u += 0x7FFFu + ((u >> 16) & 1u);   // round-to-nearest-even
    return (unsigned short)(u >> 16);
}

// ---------------------------------------------------------------------------
// Wt[n][k] = bf16(W[k][n]) : 64 x 512 bf16
__global__ void wt_kernel(const float* __restrict__ W, unsigned short* __restrict__ wt) {
    int i = blockIdx.x * blockDim.x + threadIdx.x;
    if (i < D_OUT * K_DIM) {
        int n = i >> 9;
        int k = i & 511;
        wt[i] = f32_to_bf16(W[k * D_OUT + n]);
    }
}

// ---------------------------------------------------------------------------
// h = A @ W via bf16 MFMA (unchanged from R2 for attribution).
__global__ __launch_bounds__(256) void gemm_kernel(
    const float* __restrict__ A, const unsigned short* __restrict__ wt,
    float* __restrict__ H, int n) {
    const int tid  = threadIdx.x;
    const int wv   = tid >> 6;
    const int lane = tid & 63;
    const int ln   = lane & 15;
    const int quad = lane >> 4;
    const int row0 = blockIdx.x * 64 + wv * 16;

    int arow = row0 + ln;
    if (arow >= n) arow = n - 1;
    const float* Arow = A + (size_t)arow * K_DIM;
    const unsigned short* wb = wt + (size_t)ln * K_DIM;

    floatx4 acc0 = {0.f, 0.f, 0.f, 0.f};
    floatx4 acc1 = {0.f, 0.f, 0.f, 0.f};
    floatx4 acc2 = {0.f, 0.f, 0.f, 0.f};
    floatx4 acc3 = {0.f, 0.f, 0.f, 0.f};

#pragma unroll 4
    for (int ks = 0; ks < K_DIM; ks += 32) {
        const int koff = ks + quad * 8;
        floatx4 a0 = *reinterpret_cast<const floatx4*>(Arow + koff);
        floatx4 a1 = *reinterpret_cast<const floatx4*>(Arow + koff + 4);
        short8 af;
        af[0] = (short)f32_to_bf16(a0[0]);
        af[1] = (short)f32_to_bf16(a0[1]);
        af[2] = (short)f32_to_bf16(a0[2]);
        af[3] = (short)f32_to_bf16(a0[3]);
        af[4] = (short)f32_to_bf16(a1[0]);
        af[5] = (short)f32_to_bf16(a1[1]);
        af[6] = (short)f32_to_bf16(a1[2]);
        af[7] = (short)f32_to_bf16(a1[3]);
        short8 b0 = *reinterpret_cast<const short8*>(wb + koff);
        short8 b1 = *reinterpret_cast<const short8*>(wb + 16 * K_DIM + koff);
        short8 b2 = *reinterpret_cast<const short8*>(wb + 32 * K_DIM + koff);
        short8 b3 = *reinterpret_cast<const short8*>(wb + 48 * K_DIM + koff);
        acc0 = __builtin_amdgcn_mfma_f32_16x16x32_bf16(af, b0, acc0, 0, 0, 0);
        acc1 = __builtin_amdgcn_mfma_f32_16x16x32_bf16(af, b1, acc1, 0, 0, 0);
        acc2 = __builtin_amdgcn_mfma_f32_16x16x32_bf16(af, b2, acc2, 0, 0, 0);
        acc3 = __builtin_amdgcn_mfma_f32_16x16x32_bf16(af, b3, acc3, 0, 0, 0);
    }

#pragma unroll
    for (int r = 0; r < 4; r++) {
        int gr = row0 + quad * 4 + r;
        if (gr < n) {
            float* Hr = H + (size_t)gr * D_OUT;
            Hr[ln]      = acc0[r];
            Hr[16 + ln] = acc1[r];
            Hr[32 + ln] = acc2[r];
            Hr[48 + ln] = acc3[r];
        }
    }
}

// ---------------------------------------------------------------------------
// P1: per-(chunk, bucket) histogram.  counts[b * nb + blk]
__global__ __launch_bounds__(256) void count_kernel(
    const int* __restrict__ rows, int* __restrict__ counts,
    int E, int nbuck, int nb) {
    extern __shared__ int cnt[];
    const int tid = threadIdx.x, blk = blockIdx.x;
    for (int b = tid; b < nbuck; b += 256) cnt[b] = 0;
    __syncthreads();
    const int base = blk * EPB;
#pragma unroll
    for (int i = 0; i < EPB / 256; i++) {
        int e = base + tid + i * 256;
        if (e < E) atomicAdd(&cnt[rows[e] >> RPB_SHIFT], 1);
    }
    __syncthreads();
    for (int b = tid; b < nbuck; b += 256) counts[b * nb + blk] = cnt[b];
}

// ---------------------------------------------------------------------------
// 3-phase scan (1024 elements / block)
__global__ __launch_bounds__(256) void scan1_kernel(
    const int* __restrict__ counts, int* __restrict__ bsum, int n) {
    __shared__ int wsh[4];
    const int tid = threadIdx.x, lane = tid & 63, wid = tid >> 6;
    int i0 = blockIdx.x * 1024 + tid * 4;
    int s = 0;
#pragma unroll
    for (int j = 0; j < 4; j++) {
        int ix = i0 + j;
        s += (ix < n) ? counts[ix] : 0;
    }
#pragma unroll
    for (int d = 32; d; d >>= 1) s += __shfl_xor(s, d, 64);
    if (lane == 0) wsh[wid] = s;
    __syncthreads();
    if (tid == 0) bsum[blockIdx.x] = wsh[0] + wsh[1] + wsh[2] + wsh[3];
}

__global__ __launch_bounds__(1024) void scan2_kernel(
    const int* __restrict__ bsum, int* __restrict__ bbase,
    int* __restrict__ scanned, int nblk, int L, int E) {
    __shared__ int wsum[16];
    const int tid = threadIdx.x, lane = tid & 63, wid = tid >> 6;
    int v = (tid < nblk) ? bsum[tid] : 0;
    int x = v;
#pragma unroll
    for (int d = 1; d < 64; d <<= 1) {
        int y = __shfl_up(x, d, 64);
        if (lane >= d) x += y;
    }
    if (lane == 63) wsum[wid] = x;
    __syncthreads();
    if (tid < 16) {
        int w = wsum[tid];
        int xx = w;
#pragma unroll
        for (int d = 1; d < 16; d <<= 1) {
            int y = __shfl_up(xx, d, 64);
            if (tid >= d) xx += y;
        }
        wsum[tid] = xx - w;
    }
    __syncthreads();
    if (tid < nblk) bbase[tid] = wsum[wid] + (x - v);
    if (tid == 0) scanned[L] = E;
}

__global__ __launch_bounds__(256) void scan3_kernel(
    const int* __restrict__ counts, const int* __restrict__ bbase,
    int* __restrict__ scanned, int n) {
    __shared__ int wsum[4];
    const int tid = threadIdx.x, lane = tid & 63, wid = tid >> 6;
    const int i0 = blockIdx.x * 1024 + tid * 4;
    int v[4];
#pragma unroll
    for (int j = 0; j < 4; j++) {
        int ix = i0 + j;
        v[j] = (ix < n) ? counts[ix] : 0;
    }
#pragma unroll
    for (int j = 1; j < 4; j++) v[j] += v[j - 1];
    int t = v[3];
    int x = t;
#pragma unroll
    for (int d = 1; d < 64; d <<= 1) {
        int y = __shfl_up(x, d, 64);
        if (lane >= d) x += y;
    }
    if (lane == 63) wsum[wid] = x;
    __syncthreads();
    if (tid == 0) {
        int a = 0;
#pragma unroll
        for (int w = 0; w < 4; w++) { int tmp = wsum[w]; wsum[w] = a; a += tmp; }
    }
    __syncthreads();
    int excl = bbase[blockIdx.x] + wsum[wid] + (x - t);
#pragma unroll
    for (int j = 0; j < 4; j++) {
        int ix = i0 + j;
        if (ix < n) scanned[ix] = excl + ((j == 0) ? 0 : v[j - 1]);
    }
}

// ---------------------------------------------------------------------------
// P3: partition edges into bucket-grouped packed records (col|rl<<17, val).
__global__ __launch_bounds__(256) void partition_kernel(
    const int* __restrict__ rows, const int* __restrict__ cols,
    const float* __restrict__ vals, const int* __restrict__ scanned,
    int2* __restrict__ keys, int E, int nbuck, int nb) {
    extern __shared__ int offs[];
    const int tid = threadIdx.x, blk = blockIdx.x;
    for (int b = tid; b < nbuck; b += 256) offs[b] = scanned[b * nb + blk];
    __syncthreads();
    const int base = blk * EPB;
#pragma unroll
    for (int i = 0; i < EPB / 256; i++) {
        int e = base + tid + i * 256;
        if (e < E) {
            int r = rows[e];
            int c = cols[e];
            float v = vals[e];
            int b = r >> RPB_SHIFT;
            int p = atomicAdd(&offs[b], 1);
            keys[p] = make_int2(c | ((r & (RPB - 1)) << 17), __float_as_int(v));
        }
    }
}

// ---------------------------------------------------------------------------
// P4: one block per bucket. LDS accumulator 128 rows x 64 cols (32 KB).
// Wave-uniform edge -> coalesced 256 B h-gather; LDS atomic accumulate;
// fused ReLU + coalesced float4 output.
__global__ __launch_bounds__(512) void bucket_agg_kernel(
    const float* __restrict__ h, const int2* __restrict__ keys,
    const int* __restrict__ scanned, float* __restrict__ out,
    int N, int nb) {
    __shared__ float acc[RPB * D_OUT];
    const int tid = threadIdx.x;
    const int lane = tid & 63;
    const int wv = tid >> 6;                 // 0..7
    const int b = blockIdx.x;

    // zero LDS
#pragma unroll
    for (int i = 0; i < RPB * D_OUT / 4 / 512; i++)
        ((float4*)acc)[tid + i * 512] = make_float4(0.f, 0.f, 0.f, 0.f);

    const int start = scanned[b * nb];
    const int end   = scanned[(b + 1) * nb];
    __syncthreads();

    for (int e0 = start + wv * 4; e0 < end; e0 += 32) {
#pragma unroll
        for (int j = 0; j < 4; j++) {
            int e = e0 + j;
            if (e < end) {
                int2 kv = keys[e];
                int c  = kv.x & 0x1FFFF;
                int rl = kv.x >> 17;
                float v = __int_as_float(kv.y);
                float m = v * h[(size_t)c * D_OUT + lane];
                atomicAdd(&acc[rl * D_OUT + lane], m);
            }
        }
    }
    __syncthreads();

    // write out with ReLU, float4-coalesced
    const int row0 = b * RPB;
    float4* out4 = (float4*)(out + (size_t)row0 * D_OUT);
#pragma unroll
    for (int j = 0; j < RPB * D_OUT / 4 / 512; j++) {
        int i4 = tid + j * 512;              // 0..2047
        int gr = row0 + (i4 >> 4);
        if (gr < N) {
            float4 v = ((float4*)acc)[i4];
            out4[i4] = make_float4(fmaxf(v.x, 0.f), fmaxf(v.y, 0.f),
                                   fmaxf(v.z, 0.f), fmaxf(v.w, 0.f));
        }
    }
}

// ---------------------------------------------------------------------------
extern "C" void kernel_launch(void* const* d_in, const int* in_sizes, int n_in,
                              void* d_out, int out_size, void* d_ws, size_t ws_size,
                              hipStream_t stream) {
    const float* A    = (const float*)d_in[0];
    const float* W    = (const float*)d_in[1];
    const float* vals = (const float*)d_in[2];
    const int*   rows = (const int*)d_in[3];
    const int*   cols = (const int*)d_in[4];
    float* out = (float*)d_out;

    const int N = out_size / D_OUT;              // 100000
    const int E = in_sizes[2];                   // 1600000
    const int nbuck = (N + RPB - 1) >> RPB_SHIFT;   // 782
    const int nb = (E + EPB - 1) / EPB;             // 196
    const int L = nbuck * nb;                       // 153272
    const int SB = (L + 1023) / 1024;               // 150

    // workspace layout (keys 8-aligned)
    char* ws = (char*)d_ws;
    float*          h       = (float*)ws;                                 // N*64 f32
    int2*           keys    = (int2*)(ws + (size_t)N * D_OUT * 4);        // E int2
    unsigned short* wt      = (unsigned short*)((char*)keys + (size_t)E * 8);
    int*            counts  = (int*)((char*)wt + (size_t)D_OUT * K_DIM * 2); // L
    int*            scanned = counts + L;                                 // L+1
    int*            bsum    = scanned + L + 1;                            // SB
    int*            bbase   = bsum + SB;                                  // SB

    const size_t cnt_lds = (size_t)nbuck * 4;

    wt_kernel<<<(D_OUT * K_DIM + 255) / 256, 256, 0, stream>>>(W, wt);
    gemm_kernel<<<(N + 63) / 64, 256, 0, stream>>>(A, wt, h, N);
    count_kernel<<<nb, 256, cnt_lds, stream>>>(rows, counts, E, nbuck, nb);
    scan1_kernel<<<SB, 256, 0, stream>>>(counts, bsum, L);
    scan2_kernel<<<1, 1024, 0, stream>>>(bsum, bbase, scanned, SB, L, E);
    scan3_kernel<<<SB, 256, 0, stream>>>(counts, bbase, scanned, L);
    partition_kernel<<<nb, 256, cnt_lds, stream>>>(rows, cols, vals, scanned, keys, E, nbuck, nb);
    bucket_agg_kernel<<<nbuck, 512, 0, stream>>>(h, keys, scanned, out, N, nb);
}

// Round 5
// 434.733 us; speedup vs baseline: 2.4605x; 2.4605x over previous
//
#include <hip/hip_runtime.h>
#include <hip/hip_bf16.h>

#define D_OUT 64
#define K_DIM 512
#define RPB 128            // rows per bucket (pow2)
#define RPB_SHIFT 7
#define EPB 8192           // edges per partition chunk
#define RCAP 3072          // record capacity per bucket (mean 2046, +22 sigma)

using short8  = __attribute__((ext_vector_type(8))) short;
using floatx4 = __attribute__((ext_vector_type(4))) float;

__device__ inline unsigned short f32_to_bf16(float f) {
    unsigned int u = __float_as_uint(f);
    u += 0x7FFFu + ((u >> 16) & 1u);   // round-to-nearest-even
    return (unsigned short)(u >> 16);
}

// ---------------------------------------------------------------------------
// Wt[n][k] = bf16(W[k][n]) : 64 x 512 bf16 (64 KB, L2-resident)
__global__ void wt_kernel(const float* __restrict__ W, unsigned short* __restrict__ wt) {
    int i = blockIdx.x * blockDim.x + threadIdx.x;
    if (i < D_OUT * K_DIM) {
        int n = i >> 9;
        int k = i & 511;
        wt[i] = f32_to_bf16(W[k * D_OUT + n]);
    }
}

// ---------------------------------------------------------------------------
// gemm v3: batch-issue A loads for MLP. Wave = 16 rows x 64 cols.
// Per 128-k chunk: 8 independent 16B loads/lane -> convert -> 4 MFMA steps.
__global__ __launch_bounds__(256) void gemm_kernel(
    const float* __restrict__ A, const unsigned short* __restrict__ wt,
    float* __restrict__ H, int n) {
    const int tid  = threadIdx.x;
    const int wv   = tid >> 6;
    const int lane = tid & 63;
    const int ln   = lane & 15;
    const int quad = lane >> 4;
    const int row0 = blockIdx.x * 64 + wv * 16;

    int arow = row0 + ln;
    if (arow >= n) arow = n - 1;          // clamp (stores guarded)
    const float* Arow = A + (size_t)arow * K_DIM;
    const unsigned short* wb = wt + (size_t)ln * K_DIM;

    floatx4 acc0 = {0.f, 0.f, 0.f, 0.f};
    floatx4 acc1 = {0.f, 0.f, 0.f, 0.f};
    floatx4 acc2 = {0.f, 0.f, 0.f, 0.f};
    floatx4 acc3 = {0.f, 0.f, 0.f, 0.f};

    for (int h0 = 0; h0 < K_DIM; h0 += 128) {
        // issue all 8 A-loads for this 128-k chunk (independent, batched)
        float4 t[8];
#pragma unroll
        for (int s = 0; s < 4; s++) {
            t[2 * s]     = *reinterpret_cast<const float4*>(Arow + h0 + s * 32 + quad * 8);
            t[2 * s + 1] = *reinterpret_cast<const float4*>(Arow + h0 + s * 32 + quad * 8 + 4);
        }
        // convert to bf16 fragments
        short8 ab[4];
#pragma unroll
        for (int s = 0; s < 4; s++) {
            float4 a0 = t[2 * s], a1 = t[2 * s + 1];
            short8 af;
            af[0] = (short)f32_to_bf16(a0.x);
            af[1] = (short)f32_to_bf16(a0.y);
            af[2] = (short)f32_to_bf16(a0.z);
            af[3] = (short)f32_to_bf16(a0.w);
            af[4] = (short)f32_to_bf16(a1.x);
            af[5] = (short)f32_to_bf16(a1.y);
            af[6] = (short)f32_to_bf16(a1.z);
            af[7] = (short)f32_to_bf16(a1.w);
            ab[s] = af;
        }
        // MFMA over the 4 k-steps (B from L2-hot Wt)
#pragma unroll
        for (int s = 0; s < 4; s++) {
            const int ko = h0 + s * 32 + quad * 8;
            short8 b0 = *reinterpret_cast<const short8*>(wb + ko);
            short8 b1 = *reinterpret_cast<const short8*>(wb + 16 * K_DIM + ko);
            short8 b2 = *reinterpret_cast<const short8*>(wb + 32 * K_DIM + ko);
            short8 b3 = *reinterpret_cast<const short8*>(wb + 48 * K_DIM + ko);
            acc0 = __builtin_amdgcn_mfma_f32_16x16x32_bf16(ab[s], b0, acc0, 0, 0, 0);
            acc1 = __builtin_amdgcn_mfma_f32_16x16x32_bf16(ab[s], b1, acc1, 0, 0, 0);
            acc2 = __builtin_amdgcn_mfma_f32_16x16x32_bf16(ab[s], b2, acc2, 0, 0, 0);
            acc3 = __builtin_amdgcn_mfma_f32_16x16x32_bf16(ab[s], b3, acc3, 0, 0, 0);
        }
    }

    // C/D layout: col = lane&15, row = quad*4 + reg  [m89]
#pragma unroll
    for (int r = 0; r < 4; r++) {
        int gr = row0 + quad * 4 + r;
        if (gr < n) {
            float* Hr = H + (size_t)gr * D_OUT;
            Hr[ln]      = acc0[r];
            Hr[16 + ln] = acc1[r];
            Hr[32 + ln] = acc2[r];
            Hr[48 + ln] = acc3[r];
        }
    }
}

// ---------------------------------------------------------------------------
// P1: per-(chunk, bucket) histogram.  counts[b * nb + blk]
__global__ __launch_bounds__(256) void count_kernel(
    const int* __restrict__ rows, int* __restrict__ counts,
    int E, int nbuck, int nb) {
    extern __shared__ int cnt[];
    const int tid = threadIdx.x, blk = blockIdx.x;
    for (int b = tid; b < nbuck; b += 256) cnt[b] = 0;
    __syncthreads();
    const int base = blk * EPB;
#pragma unroll
    for (int i = 0; i < EPB / 256; i++) {
        int e = base + tid + i * 256;
        if (e < E) atomicAdd(&cnt[rows[e] >> RPB_SHIFT], 1);
    }
    __syncthreads();
    for (int b = tid; b < nbuck; b += 256) counts[b * nb + blk] = cnt[b];
}

// ---------------------------------------------------------------------------
// 3-phase scan (1024 elements / block)
__global__ __launch_bounds__(256) void scan1_kernel(
    const int* __restrict__ counts, int* __restrict__ bsum, int n) {
    __shared__ int wsh[4];
    const int tid = threadIdx.x, lane = tid & 63, wid = tid >> 6;
    int i0 = blockIdx.x * 1024 + tid * 4;
    int s = 0;
#pragma unroll
    for (int j = 0; j < 4; j++) {
        int ix = i0 + j;
        s += (ix < n) ? counts[ix] : 0;
    }
#pragma unroll
    for (int d = 32; d; d >>= 1) s += __shfl_xor(s, d, 64);
    if (lane == 0) wsh[wid] = s;
    __syncthreads();
    if (tid == 0) bsum[blockIdx.x] = wsh[0] + wsh[1] + wsh[2] + wsh[3];
}

__global__ __launch_bounds__(1024) void scan2_kernel(
    const int* __restrict__ bsum, int* __restrict__ bbase,
    int* __restrict__ scanned, int nblk, int L, int E) {
    __shared__ int wsum[16];
    const int tid = threadIdx.x, lane = tid & 63, wid = tid >> 6;
    int v = (tid < nblk) ? bsum[tid] : 0;
    int x = v;
#pragma unroll
    for (int d = 1; d < 64; d <<= 1) {
        int y = __shfl_up(x, d, 64);
        if (lane >= d) x += y;
    }
    if (lane == 63) wsum[wid] = x;
    __syncthreads();
    if (tid < 16) {
        int w = wsum[tid];
        int xx = w;
#pragma unroll
        for (int d = 1; d < 16; d <<= 1) {
            int y = __shfl_up(xx, d, 64);
            if (tid >= d) xx += y;
        }
        wsum[tid] = xx - w;
    }
    __syncthreads();
    if (tid < nblk) bbase[tid] = wsum[wid] + (x - v);
    if (tid == 0) scanned[L] = E;
}

__global__ __launch_bounds__(256) void scan3_kernel(
    const int* __restrict__ counts, const int* __restrict__ bbase,
    int* __restrict__ scanned, int n) {
    __shared__ int wsum[4];
    const int tid = threadIdx.x, lane = tid & 63, wid = tid >> 6;
    const int i0 = blockIdx.x * 1024 + tid * 4;
    int v[4];
#pragma unroll
    for (int j = 0; j < 4; j++) {
        int ix = i0 + j;
        v[j] = (ix < n) ? counts[ix] : 0;
    }
#pragma unroll
    for (int j = 1; j < 4; j++) v[j] += v[j - 1];
    int t = v[3];
    int x = t;
#pragma unroll
    for (int d = 1; d < 64; d <<= 1) {
        int y = __shfl_up(x, d, 64);
        if (lane >= d) x += y;
    }
    if (lane == 63) wsum[wid] = x;
    __syncthreads();
    if (tid == 0) {
        int a = 0;
#pragma unroll
        for (int w = 0; w < 4; w++) { int tmp = wsum[w]; wsum[w] = a; a += tmp; }
    }
    __syncthreads();
    int excl = bbase[blockIdx.x] + wsum[wid] + (x - t);
#pragma unroll
    for (int j = 0; j < 4; j++) {
        int ix = i0 + j;
        if (ix < n) scanned[ix] = excl + ((j == 0) ? 0 : v[j - 1]);
    }
}

// ---------------------------------------------------------------------------
// P3: partition edges into bucket-grouped packed records (col | rl<<17, val).
__global__ __launch_bounds__(256) void partition_kernel(
    const int* __restrict__ rows, const int* __restrict__ cols,
    const float* __restrict__ vals, const int* __restrict__ scanned,
    int2* __restrict__ keys, int E, int nbuck, int nb) {
    extern __shared__ int offs[];
    const int tid = threadIdx.x, blk = blockIdx.x;
    for (int b = tid; b < nbuck; b += 256) offs[b] = scanned[b * nb + blk];
    __syncthreads();
    const int base = blk * EPB;
#pragma unroll
    for (int i = 0; i < EPB / 256; i++) {
        int e = base + tid + i * 256;
        if (e < E) {
            int r = rows[e];
            int c = cols[e];
            float v = vals[e];
            int b = r >> RPB_SHIFT;
            int p = atomicAdd(&offs[b], 1);
            keys[p] = make_int2(c | ((r & (RPB - 1)) << 17), __float_as_int(v));
        }
    }
}

// ---------------------------------------------------------------------------
// P4: one block per bucket. LDS counting sort by row-local, then wave-per-row
// register accumulation (no atomics in hot loop), fused ReLU store.
__global__ __launch_bounds__(512) void sort_agg_kernel(
    const float* __restrict__ h, const int2* __restrict__ keys,
    const int* __restrict__ scanned, float* __restrict__ out,
    int N, int nb) {
    __shared__ int2 rec[RCAP];
    __shared__ int cnt[RPB];
    __shared__ int excl[RPB];
    __shared__ int cur[RPB];
    __shared__ int wtot[2];

    const int tid  = threadIdx.x;
    const int lane = tid & 63;
    const int wv   = tid >> 6;           // 0..7
    const int b    = blockIdx.x;

    const int start = scanned[b * nb];
    const int end   = scanned[(b + 1) * nb];
    const int m     = end - start;

    if (tid < RPB) cnt[tid] = 0;
    __syncthreads();

    // count rows
    for (int i = tid; i < m; i += 512) {
        int rl = keys[start + i].x >> 17;
        atomicAdd(&cnt[rl], 1);
    }
    __syncthreads();

    // exclusive scan of 128 counters (2 waves)
    int v = 0, x = 0;
    if (tid < RPB) {
        v = cnt[tid];
        x = v;
#pragma unroll
        for (int d = 1; d < 64; d <<= 1) {
            int y = __shfl_up(x, d, 64);
            if (lane >= d) x += y;
        }
        if (lane == 63) wtot[tid >> 6] = x;
    }
    __syncthreads();
    if (tid < RPB) {
        int base = (tid >= 64) ? wtot[0] : 0;
        int ex = base + x - v;
        excl[tid] = ex;
        cur[tid]  = ex;
    }
    __syncthreads();

    // scatter into row-sorted LDS positions
    for (int i = tid; i < m; i += 512) {
        int2 kv = keys[start + i];
        int rl = kv.x >> 17;
        int p = atomicAdd(&cur[rl], 1);
        if (p < RCAP) rec[p] = kv;
    }
    __syncthreads();

    // aggregate: wave per row, lane = column, 4-deep independent gathers
    const int row0 = b * RPB;
    for (int rl = wv; rl < RPB; rl += 8) {
        int s = excl[rl];
        int e = cur[rl];                 // = excl + count
        float acc = 0.f;
        int j = s;
        for (; j + 4 <= e; j += 4) {
            int2 k0 = rec[j], k1 = rec[j + 1], k2 = rec[j + 2], k3 = rec[j + 3];
            float g0 = h[(size_t)(k0.x & 0x1FFFF) * D_OUT + lane];
            float g1 = h[(size_t)(k1.x & 0x1FFFF) * D_OUT + lane];
            float g2 = h[(size_t)(k2.x & 0x1FFFF) * D_OUT + lane];
            float g3 = h[(size_t)(k3.x & 0x1FFFF) * D_OUT + lane];
            acc += __int_as_float(k0.y) * g0;
            acc += __int_as_float(k1.y) * g1;
            acc += __int_as_float(k2.y) * g2;
            acc += __int_as_float(k3.y) * g3;
        }
        for (; j < e; j++) {
            int2 kv = rec[j];
            acc += __int_as_float(kv.y) * h[(size_t)(kv.x & 0x1FFFF) * D_OUT + lane];
        }
        int gr = row0 + rl;
        if (gr < N) out[(size_t)gr * D_OUT + lane] = fmaxf(acc, 0.f);
    }
}

// ---------------------------------------------------------------------------
extern "C" void kernel_launch(void* const* d_in, const int* in_sizes, int n_in,
                              void* d_out, int out_size, void* d_ws, size_t ws_size,
                              hipStream_t stream) {
    const float* A    = (const float*)d_in[0];
    const float* W    = (const float*)d_in[1];
    const float* vals = (const float*)d_in[2];
    const int*   rows = (const int*)d_in[3];
    const int*   cols = (const int*)d_in[4];
    float* out = (float*)d_out;

    const int N = out_size / D_OUT;                 // 100000
    const int E = in_sizes[2];                      // 1600000
    const int nbuck = (N + RPB - 1) >> RPB_SHIFT;   // 782
    const int nb = (E + EPB - 1) / EPB;             // 196
    const int L = nbuck * nb;                       // 153272
    const int SB = (L + 1023) / 1024;               // 150

    // workspace layout (keys 8-aligned)
    char* ws = (char*)d_ws;
    float*          h       = (float*)ws;                                 // N*64 f32
    int2*           keys    = (int2*)(ws + (size_t)N * D_OUT * 4);        // E int2
    unsigned short* wt      = (unsigned short*)((char*)keys + (size_t)E * 8);
    int*            counts  = (int*)((char*)wt + (size_t)D_OUT * K_DIM * 2); // L
    int*            scanned = counts + L;                                 // L+1
    int*            bsum    = scanned + L + 1;                            // SB
    int*            bbase   = bsum + SB;                                  // SB

    const size_t cnt_lds = (size_t)nbuck * 4;

    wt_kernel<<<(D_OUT * K_DIM + 255) / 256, 256, 0, stream>>>(W, wt);
    gemm_kernel<<<(N + 63) / 64, 256, 0, stream>>>(A, wt, h, N);
    count_kernel<<<nb, 256, cnt_lds, stream>>>(rows, counts, E, nbuck, nb);
    scan1_kernel<<<SB, 256, 0, stream>>>(counts, bsum, L);
    scan2_kernel<<<1, 1024, 0, stream>>>(bsum, bbase, scanned, SB, L, E);
    scan3_kernel<<<SB, 256, 0, stream>>>(counts, bbase, scanned, L);
    partition_kernel<<<nb, 256, cnt_lds, stream>>>(rows, cols, vals, scanned, keys, E, nbuck, nb);
    sort_agg_kernel<<<nbuck, 512, 0, stream>>>(h, keys, scanned, out, N, nb);
}